// Round 2
// baseline (281.400 us; speedup 1.0000x reference)
//
#include <hip/hip_runtime.h>

#define NN 4
#define TT 24
#define CC 4
#define HH 256
#define WW 256
#define NT 96            // NN*TT
#define HWP 65536        // HH*WW

// ---------------- 1) per-(nt,c) min/max, c in {0,1,2} ----------------
__global__ __launch_bounds__(256) void k_minmax(const float* __restrict__ x,
                                                float* __restrict__ mm) {
    int bid = blockIdx.x;          // 0..287
    int c  = bid % 3;
    int nt = bid / 3;
    const float4* p = (const float4*)(x + ((size_t)nt * CC + c) * HWP);
    int tid = threadIdx.x;         // 256 threads
    float vmin = 1e30f, vmax = -1e30f;
    // 65536 floats = 16384 float4 = 64 per thread
    for (int it = 0; it < 64; ++it) {
        float4 v = p[it * 256 + tid];
        vmin = fminf(vmin, fminf(fminf(v.x, v.y), fminf(v.z, v.w)));
        vmax = fmaxf(vmax, fmaxf(fmaxf(v.x, v.y), fmaxf(v.z, v.w)));
    }
    // wave64 reduce
    for (int off = 32; off > 0; off >>= 1) {
        vmin = fminf(vmin, __shfl_down(vmin, off));
        vmax = fmaxf(vmax, __shfl_down(vmax, off));
    }
    __shared__ float smin[4], smax[4];
    if ((tid & 63) == 0) { smin[tid >> 6] = vmin; smax[tid >> 6] = vmax; }
    __syncthreads();
    if (tid == 0) {
        float a = fminf(fminf(smin[0], smin[1]), fminf(smin[2], smin[3]));
        float b = fmaxf(fmaxf(smax[0], smax[1]), fmaxf(smax[2], smax[3]));
        mm[bid * 2]     = a;
        mm[bid * 2 + 1] = b;
    }
}

// ---------------- 2) argmin over t of |182 - dates| ----------------
__global__ void k_argmin(const int* __restrict__ dates, int* __restrict__ tidx) {
    int n = threadIdx.x;
    if (n < NN) {
        int d0 = 182 - dates[n * TT];
        int bestv = d0 < 0 ? -d0 : d0;
        int best = 0;
        for (int t = 1; t < TT; ++t) {
            int d = 182 - dates[n * TT + t];
            d = d < 0 ? -d : d;
            if (d < bestv) { bestv = d; best = t; }   // strict < keeps first occurrence
        }
        tidx[n] = best;
    }
}

// ---------------- 3) normalize + gray -> x_pairs channel 0 ----------------
__global__ __launch_bounds__(256) void k_gray(const float* __restrict__ x,
                                              const float* __restrict__ mm,
                                              float* __restrict__ xp) {
    int gid = blockIdx.x * 256 + threadIdx.x;   // 0 .. NT*16384-1
    int nt = gid >> 14;                          // 16384 float4 per image
    int g  = gid & 16383;
    const float4* p0 = (const float4*)(x + ((size_t)nt * CC + 0) * HWP);
    const float4* p1 = (const float4*)(x + ((size_t)nt * CC + 1) * HWP);
    const float4* p2 = (const float4*)(x + ((size_t)nt * CC + 2) * HWP);
    float mn0 = mm[(nt * 3 + 0) * 2], mx0 = mm[(nt * 3 + 0) * 2 + 1];
    float mn1 = mm[(nt * 3 + 1) * 2], mx1 = mm[(nt * 3 + 1) * 2 + 1];
    float mn2 = mm[(nt * 3 + 2) * 2], mx2 = mm[(nt * 3 + 2) * 2 + 1];
    float s0 = 0.299f / (mx0 - mn0 + 1e-8f);
    float s1 = 0.587f / (mx1 - mn1 + 1e-8f);
    float s2 = 0.114f / (mx2 - mn2 + 1e-8f);
    float bias = -(mn0 * s0 + mn1 * s1 + mn2 * s2);
    float4 v0 = p0[g], v1 = p1[g], v2 = p2[g];
    float4 r;
    r.x = v0.x * s0 + v1.x * s1 + v2.x * s2 + bias;
    r.y = v0.y * s0 + v1.y * s1 + v2.y * s2 + bias;
    r.z = v0.z * s0 + v1.z * s1 + v2.z * s2 + bias;
    r.w = v0.w * s0 + v1.w * s1 + v2.w * s2 + bias;
    ((float4*)(xp + ((size_t)nt * 2) * HWP))[g] = r;   // channel 0
}

// ---------------- 4) broadcast ref slice -> x_pairs channel 1 ----------------
// Source slice per n is 256 KB -> L2/L3-served after first touch; writes spread evenly.
__global__ __launch_bounds__(256) void k_refcast(const int* __restrict__ tidx,
                                                 float* __restrict__ xp) {
    int gid = blockIdx.x * 256 + threadIdx.x;
    int nt = gid >> 14;
    int g  = gid & 16383;
    int n  = nt / TT;
    int ti = tidx[n];
    float4 v = ((const float4*)(xp + ((size_t)(n * TT + ti) * 2) * HWP))[g];
    ((float4*)(xp + ((size_t)nt * 2 + 1) * HWP))[g] = v;
}

// ---------------- 5) bilinear translation (zeros padding), 4 px/thread ----------------
__global__ __launch_bounds__(256) void k_bilinear(const float* __restrict__ x,
                                                  const float* __restrict__ thetas,
                                                  float* __restrict__ out) {
    int idx = blockIdx.x * 256 + threadIdx.x;   // quad index, 0..6,291,455
    int q   = idx & 63;         // quad-in-row (W/4 = 64)
    int row = idx >> 6;         // bc*H + i
    int i   = row & 255;
    int bc  = row >> 8;         // 0..383  (= b*C + c)
    int b   = bc >> 2;
    float tx = thetas[2 * b];
    float ty = thetas[2 * b + 1];
    float sy = (float)i - ty;
    float y0f = floorf(sy);
    float wy  = sy - y0f;
    int   y0  = (int)y0f;
    int   j   = q << 2;
    float sx  = (float)j - tx;
    float x0f = floorf(sx);
    float wx  = sx - x0f;
    int   x0  = (int)x0f;
    const float* img = x + (size_t)bc * HWP;
    bool ry0 = ((unsigned)y0 < 256u);
    bool ry1 = ((unsigned)(y0 + 1) < 256u);
    const float* r0 = img + y0 * 256;
    const float* r1 = r0 + 256;
    float a[5], bb[5];
    #pragma unroll
    for (int k = 0; k < 5; ++k) {
        int xc = x0 + k;
        bool vx = ((unsigned)xc < 256u);
        a[k]  = (ry0 && vx) ? r0[xc] : 0.f;
        bb[k] = (ry1 && vx) ? r1[xc] : 0.f;
    }
    float wy0 = 1.f - wy;
    float wx0 = 1.f - wx;
    float c[5];
    #pragma unroll
    for (int k = 0; k < 5; ++k) c[k] = wy0 * a[k] + wy * bb[k];
    float4 o;
    o.x = wx0 * c[0] + wx * c[1];
    o.y = wx0 * c[1] + wx * c[2];
    o.z = wx0 * c[2] + wx * c[3];
    o.w = wx0 * c[3] + wx * c[4];
    ((float4*)(out + (size_t)bc * HWP + (size_t)i * 256 + j))[0] = o;  // j%4==0 -> 16B aligned
}

extern "C" void kernel_launch(void* const* d_in, const int* in_sizes, int n_in,
                              void* d_out, int out_size, void* d_ws, size_t ws_size,
                              hipStream_t stream) {
    const float* x      = (const float*)d_in[0];
    const int*   dates  = (const int*)d_in[1];
    const float* thetas = (const float*)d_in[2];
    float* out1 = (float*)d_out;                      // (n,t,c,h,w) bilinear output
    float* out2 = out1 + (size_t)NT * CC * HWP;       // x_pairs (n,t,2,h,w)
    float* mm   = (float*)d_ws;                       // 288*2 floats
    int*   tidx = (int*)((char*)d_ws + 4096);         // 4 ints

    k_minmax  <<<288,   256, 0, stream>>>(x, mm);
    k_argmin  <<<1,      64, 0, stream>>>(dates, tidx);
    k_gray    <<<6144,  256, 0, stream>>>(x, mm, out2);
    k_refcast <<<6144,  256, 0, stream>>>(tidx, out2);
    k_bilinear<<<24576, 256, 0, stream>>>(x, thetas, out1);
}

// Round 3
// 252.279 us; speedup vs baseline: 1.1154x; 1.1154x over previous
//
#include <hip/hip_runtime.h>

#define NN 4
#define TT 24
#define CC 4
#define HH 256
#define WW 256
#define NT 96            // NN*TT
#define HWP 65536        // HH*WW

// ============ 1) per-(nt,c) min/max partials: 4 blocks per channel ============
// grid 1152: bid -> ch = bid>>2 (nt*3+c), s = bid&3 (quarter). Writes part[bid*2 +{0,1}].
__global__ __launch_bounds__(256) void k_minmax_part(const float* __restrict__ x,
                                                     float* __restrict__ part) {
    int bid = blockIdx.x;
    int s  = bid & 3;
    int ch = bid >> 2;       // 0..287
    int c  = ch % 3;
    int nt = ch / 3;
    const float4* p = (const float4*)(x + ((size_t)nt * CC + c) * HWP) + s * 4096;
    int tid = threadIdx.x;
    float vmin = 1e30f, vmax = -1e30f;
    #pragma unroll
    for (int it = 0; it < 16; ++it) {          // 4096 float4 / 256 threads
        float4 v = p[it * 256 + tid];
        vmin = fminf(vmin, fminf(fminf(v.x, v.y), fminf(v.z, v.w)));
        vmax = fmaxf(vmax, fmaxf(fmaxf(v.x, v.y), fmaxf(v.z, v.w)));
    }
    for (int off = 32; off > 0; off >>= 1) {
        vmin = fminf(vmin, __shfl_down(vmin, off));
        vmax = fmaxf(vmax, __shfl_down(vmax, off));
    }
    __shared__ float smin[4], smax[4];
    if ((tid & 63) == 0) { smin[tid >> 6] = vmin; smax[tid >> 6] = vmax; }
    __syncthreads();
    if (tid == 0) {
        part[bid * 2]     = fminf(fminf(smin[0], smin[1]), fminf(smin[2], smin[3]));
        part[bid * 2 + 1] = fmaxf(fmaxf(smax[0], smax[1]), fmaxf(smax[2], smax[3]));
    }
}

// ============ 2) gray (both x_pairs channels) + inline combine + inline argmin ============
// grid 6144: 64 blocks per nt; block handles 256 float4 of one image plane.
__global__ __launch_bounds__(256) void k_gray2(const float* __restrict__ x,
                                               const float* __restrict__ part,
                                               const int* __restrict__ dates,
                                               float* __restrict__ xp) {
    int bid = blockIdx.x;
    int nt  = bid >> 6;                       // uniform per block
    int g   = (bid & 63) * 256 + threadIdx.x; // float4 index within plane
    int n   = nt / TT;

    // argmin over t of |182 - dates[n,t]| (uniform addresses -> scalar loads)
    int bestv = 0x7FFFFFFF, best = 0;
    for (int t = 0; t < TT; ++t) {
        int d = 182 - dates[n * TT + t];
        d = d < 0 ? -d : d;
        if (d < bestv) { bestv = d; best = t; }
    }
    int nt2 = n * TT + best;

    // combine 4 partials per channel for nt and nt2
    float sA[3], sB[3], biasA = 0.f, biasB = 0.f;
    const float w[3] = {0.299f, 0.587f, 0.114f};
    #pragma unroll
    for (int c = 0; c < 3; ++c) {
        int chA = nt * 3 + c, chB = nt2 * 3 + c;
        float mnA = 1e30f, mxA = -1e30f, mnB = 1e30f, mxB = -1e30f;
        #pragma unroll
        for (int s = 0; s < 4; ++s) {
            mnA = fminf(mnA, part[(chA * 4 + s) * 2]);
            mxA = fmaxf(mxA, part[(chA * 4 + s) * 2 + 1]);
            mnB = fminf(mnB, part[(chB * 4 + s) * 2]);
            mxB = fmaxf(mxB, part[(chB * 4 + s) * 2 + 1]);
        }
        sA[c] = w[c] / (mxA - mnA + 1e-8f);  biasA -= mnA * sA[c];
        sB[c] = w[c] / (mxB - mnB + 1e-8f);  biasB -= mnB * sB[c];
    }

    const float4* pA0 = (const float4*)(x + ((size_t)nt  * CC + 0) * HWP);
    const float4* pA1 = (const float4*)(x + ((size_t)nt  * CC + 1) * HWP);
    const float4* pA2 = (const float4*)(x + ((size_t)nt  * CC + 2) * HWP);
    const float4* pB0 = (const float4*)(x + ((size_t)nt2 * CC + 0) * HWP);
    const float4* pB1 = (const float4*)(x + ((size_t)nt2 * CC + 1) * HWP);
    const float4* pB2 = (const float4*)(x + ((size_t)nt2 * CC + 2) * HWP);

    float4 v0 = pA0[g], v1 = pA1[g], v2 = pA2[g];
    float4 rA;
    rA.x = v0.x * sA[0] + v1.x * sA[1] + v2.x * sA[2] + biasA;
    rA.y = v0.y * sA[0] + v1.y * sA[1] + v2.y * sA[2] + biasA;
    rA.z = v0.z * sA[0] + v1.z * sA[1] + v2.z * sA[2] + biasA;
    rA.w = v0.w * sA[0] + v1.w * sA[1] + v2.w * sA[2] + biasA;
    ((float4*)(xp + ((size_t)nt * 2) * HWP))[g] = rA;         // channel 0

    float4 u0 = pB0[g], u1 = pB1[g], u2 = pB2[g];             // hot in L2/L3 (3 MB unique)
    float4 rB;
    rB.x = u0.x * sB[0] + u1.x * sB[1] + u2.x * sB[2] + biasB;
    rB.y = u0.y * sB[0] + u1.y * sB[1] + u2.y * sB[2] + biasB;
    rB.z = u0.z * sB[0] + u1.z * sB[1] + u2.z * sB[2] + biasB;
    rB.w = u0.w * sB[0] + u1.w * sB[1] + u2.w * sB[2] + biasB;
    ((float4*)(xp + ((size_t)nt * 2 + 1) * HWP))[g] = rB;     // channel 1
}

// ============ 3) bilinear translation via LDS row staging ============
// Translation-only => D=floor(-tx), E=floor(-ty), wx, wy constant per image.
// Block = 4 output rows of one (b,c) plane; stages 5 input rows (272-float
// zero-padded window aligned to the image float4 grid) in LDS.
__global__ __launch_bounds__(256) void k_shift(const float* __restrict__ x,
                                               const float* __restrict__ thetas,
                                               float* __restrict__ out) {
    __shared__ float lds[5][272];
    int bid   = blockIdx.x;
    int strip = bid & 63;            // 64 strips of 4 rows
    int bc    = bid >> 6;            // 0..383
    int b     = bc >> 2;
    float tx = thetas[2 * b];
    float ty = thetas[2 * b + 1];
    int   D  = (int)floorf(-tx);
    int   E  = (int)floorf(-ty);
    float wx = -tx - (float)D;       // frac, in [0,1)
    float wy = -ty - (float)E;
    int x_lo = (D - 4) & ~3;         // aligned window start; off = D-x_lo in [4,7]
    int s    = (D - x_lo) - 4;       // uniform shift in [0,3]
    int i0   = strip * 4;
    int y_base = i0 + E;
    const float* img = x + (size_t)bc * HWP;

    int tid = threadIdx.x;
    // stage 5 rows x 68 float4 slots, zero-padding rows/cols outside the image
    for (int t = tid; t < 340; t += 256) {
        int r = t / 68;
        int m = t - r * 68;
        int y = y_base + r;
        int sx4 = x_lo + 4 * m;
        float4 v = make_float4(0.f, 0.f, 0.f, 0.f);
        if ((unsigned)y < 256u && (unsigned)sx4 <= 252u)
            v = *(const float4*)(img + y * 256 + sx4);
        *(float4*)&lds[r][4 * m] = v;
    }
    __syncthreads();

    int r_o = tid >> 6;              // output row within strip
    int q   = tid & 63;              // output quad (j = 4q)
    const float* L0 = &lds[r_o][4 * q + 4];
    const float* L1 = &lds[r_o + 1][4 * q + 4];
    float4 a0 = *(const float4*)(L0);
    float4 a1 = *(const float4*)(L0 + 4);
    float4 b0 = *(const float4*)(L1);
    float4 b1 = *(const float4*)(L1 + 4);

    float rr[8];
    rr[0] = a0.x + wy * (b0.x - a0.x);
    rr[1] = a0.y + wy * (b0.y - a0.y);
    rr[2] = a0.z + wy * (b0.z - a0.z);
    rr[3] = a0.w + wy * (b0.w - a0.w);
    rr[4] = a1.x + wy * (b1.x - a1.x);
    rr[5] = a1.y + wy * (b1.y - a1.y);
    rr[6] = a1.z + wy * (b1.z - a1.z);
    rr[7] = a1.w + wy * (b1.w - a1.w);

    float4 o;
    #define COLLERP(e0,e1,e2,e3,e4) \
        o.x = rr[e0] + wx * (rr[e1] - rr[e0]); \
        o.y = rr[e1] + wx * (rr[e2] - rr[e1]); \
        o.z = rr[e2] + wx * (rr[e3] - rr[e2]); \
        o.w = rr[e3] + wx * (rr[e4] - rr[e3]);
    switch (s) {                     // wave-uniform branch
        case 0: COLLERP(0,1,2,3,4); break;
        case 1: COLLERP(1,2,3,4,5); break;
        case 2: COLLERP(2,3,4,5,6); break;
        default: COLLERP(3,4,5,6,7); break;
    }
    #undef COLLERP

    *(float4*)(out + (size_t)bc * HWP + (size_t)(i0 + r_o) * 256 + 4 * q) = o;
}

extern "C" void kernel_launch(void* const* d_in, const int* in_sizes, int n_in,
                              void* d_out, int out_size, void* d_ws, size_t ws_size,
                              hipStream_t stream) {
    const float* x      = (const float*)d_in[0];
    const int*   dates  = (const int*)d_in[1];
    const float* thetas = (const float*)d_in[2];
    float* out1 = (float*)d_out;                      // (n,t,c,h,w) bilinear output
    float* out2 = out1 + (size_t)NT * CC * HWP;       // x_pairs (n,t,2,h,w)
    float* part = (float*)d_ws;                       // 1152*2 floats

    k_minmax_part<<<1152,  256, 0, stream>>>(x, part);
    k_gray2      <<<6144,  256, 0, stream>>>(x, part, dates, out2);
    k_shift      <<<24576, 256, 0, stream>>>(x, thetas, out1);
}

// Round 4
// 252.139 us; speedup vs baseline: 1.1161x; 1.0006x over previous
//
#include <hip/hip_runtime.h>

#define NN 4
#define TT 24
#define CC 4
#define NT 96            // NN*TT
#define HWP 65536        // 256*256
#define NSLOT 33         // 32 strip partials + 1 edge partial per (nt,c)

// ================= L1: fused bilinear-shift + min/max partials =================
// Translation-only => D=floor(-tx), E=floor(-ty), wx, wy constant per image.
// grid = 6144 strip blocks (bc = bid>>4, 16-row strips) + 288 edge blocks.
// Strip blocks stage 17 rows x 272 cols (zero-padded, float4-aligned window),
// emit 16 output rows, and accumulate min/max over the VALID staged elements
// (idempotent across overlapping strips). Edge blocks sweep the rows/columns
// no strip window ever stages, so the union covers every pixel exactly.
__global__ __launch_bounds__(256) void k_shift_mm(const float* __restrict__ x,
                                                  const float* __restrict__ thetas,
                                                  float* __restrict__ out,
                                                  float* __restrict__ part) {
    __shared__ float lds[17][272];
    __shared__ float smin[4], smax[4];
    int bid = blockIdx.x;
    int tid = threadIdx.x;
    float vmin = 1e30f, vmax = -1e30f;

    if (bid < 6144) {
        int strip = bid & 15;
        int bc    = bid >> 4;        // 0..383
        int b     = bc >> 2;         // nt
        int c     = bc & 3;
        float tx = thetas[2 * b];
        float ty = thetas[2 * b + 1];
        int   D  = (int)floorf(-tx);
        int   E  = (int)floorf(-ty);
        float wx = -tx - (float)D;
        float wy = -ty - (float)E;
        int x_lo = (D - 4) & ~3;     // aligned window start
        int s    = (D - x_lo) - 4;   // uniform shift in [0,3]
        int i0   = strip * 16;
        int y_base = i0 + E;
        const float* img = x + (size_t)bc * HWP;
        bool trackmm = (c < 3);

        for (int t = tid; t < 17 * 68; t += 256) {
            int r = t / 68;
            int m = t - r * 68;
            int y = y_base + r;
            int sx4 = x_lo + 4 * m;
            float4 v = make_float4(0.f, 0.f, 0.f, 0.f);
            if ((unsigned)y < 256u && (unsigned)sx4 <= 252u) {
                v = *(const float4*)(img + y * 256 + sx4);
                if (trackmm) {
                    vmin = fminf(vmin, fminf(fminf(v.x, v.y), fminf(v.z, v.w)));
                    vmax = fmaxf(vmax, fmaxf(fmaxf(v.x, v.y), fmaxf(v.z, v.w)));
                }
            }
            *(float4*)&lds[r][4 * m] = v;
        }
        for (int off = 32; off > 0; off >>= 1) {
            vmin = fminf(vmin, __shfl_down(vmin, off));
            vmax = fmaxf(vmax, __shfl_down(vmax, off));
        }
        if ((tid & 63) == 0) { smin[tid >> 6] = vmin; smax[tid >> 6] = vmax; }
        __syncthreads();             // guards lds staging AND smin/smax
        if (tid == 0 && trackmm) {
            int ch = b * 3 + c;
            part[(ch * NSLOT + strip) * 2]     = fminf(fminf(smin[0], smin[1]), fminf(smin[2], smin[3]));
            part[(ch * NSLOT + strip) * 2 + 1] = fmaxf(fmaxf(smax[0], smax[1]), fmaxf(smax[2], smax[3]));
        }

        int w = tid >> 6, q = tid & 63;
        float* outp = out + (size_t)bc * HWP + (size_t)i0 * 256 + 4 * q;
        #pragma unroll
        for (int k = 0; k < 4; ++k) {
            int r = 4 * w + k;
            const float* L0 = &lds[r][4 * q + 4];
            const float* L1 = &lds[r + 1][4 * q + 4];
            float4 a0 = *(const float4*)(L0);
            float4 a1 = *(const float4*)(L0 + 4);
            float4 b0 = *(const float4*)(L1);
            float4 b1 = *(const float4*)(L1 + 4);
            float rr[8];
            rr[0] = a0.x + wy * (b0.x - a0.x);
            rr[1] = a0.y + wy * (b0.y - a0.y);
            rr[2] = a0.z + wy * (b0.z - a0.z);
            rr[3] = a0.w + wy * (b0.w - a0.w);
            rr[4] = a1.x + wy * (b1.x - a1.x);
            rr[5] = a1.y + wy * (b1.y - a1.y);
            rr[6] = a1.z + wy * (b1.z - a1.z);
            rr[7] = a1.w + wy * (b1.w - a1.w);
            float4 o;
            #define COLLERP(e0,e1,e2,e3,e4) \
                o.x = rr[e0] + wx * (rr[e1] - rr[e0]); \
                o.y = rr[e1] + wx * (rr[e2] - rr[e1]); \
                o.z = rr[e2] + wx * (rr[e3] - rr[e2]); \
                o.w = rr[e3] + wx * (rr[e4] - rr[e3]);
            switch (s) {             // wave-uniform
                case 0: COLLERP(0,1,2,3,4); break;
                case 1: COLLERP(1,2,3,4,5); break;
                case 2: COLLERP(2,3,4,5,6); break;
                default: COLLERP(3,4,5,6,7); break;
            }
            #undef COLLERP
            *(float4*)(outp + (size_t)r * 256) = o;
        }
    } else {
        // -------- edge block: pixels never staged by any strip window --------
        int ch = bid - 6144;         // 0..287
        int c  = ch % 3;
        int nt = ch / 3;
        float tx = thetas[2 * nt];
        float ty = thetas[2 * nt + 1];
        int D = (int)floorf(-tx);
        int E = (int)floorf(-ty);
        int x_lo = (D - 4) & ~3;
        const float4* img4 = (const float4*)(x + ((size_t)nt * CC + c) * HWP);

        // rows never staged: E>0 -> [0,E); E<0 -> [257+E, 256)
        int rlo, rhi;
        if (E > 0)      { rlo = 0; rhi = E > 256 ? 256 : E; }
        else if (E < 0) { rlo = 257 + E; if (rlo < 0) rlo = 0; rhi = 256; }
        else            { rlo = 0; rhi = 0; }
        for (int t = tid; t < (rhi - rlo) * 64; t += 256) {
            float4 v = img4[(rlo + (t >> 6)) * 64 + (t & 63)];
            vmin = fminf(vmin, fminf(fminf(v.x, v.y), fminf(v.z, v.w)));
            vmax = fmaxf(vmax, fmaxf(fmaxf(v.x, v.y), fmaxf(v.z, v.w)));
        }
        // columns never staged, all rows: [0, x_lo) and [x_lo+272, 256)
        int cl = x_lo; if (cl < 0) cl = 0; if (cl > 256) cl = 256;
        int w4l = cl >> 2;
        if (w4l > 0) {
            for (int t = tid; t < 256 * w4l; t += 256) {
                int row = t / w4l;
                int m   = t - row * w4l;
                float4 v = img4[row * 64 + m];
                vmin = fminf(vmin, fminf(fminf(v.x, v.y), fminf(v.z, v.w)));
                vmax = fmaxf(vmax, fmaxf(fmaxf(v.x, v.y), fmaxf(v.z, v.w)));
            }
        }
        int cu = x_lo + 272; if (cu < 0) cu = 0; if (cu > 256) cu = 256;
        int u4 = cu >> 2, w4u = 64 - u4;
        if (w4u > 0) {
            for (int t = tid; t < 256 * w4u; t += 256) {
                int row = t / w4u;
                int m   = u4 + (t - row * w4u);
                float4 v = img4[row * 64 + m];
                vmin = fminf(vmin, fminf(fminf(v.x, v.y), fminf(v.z, v.w)));
                vmax = fmaxf(vmax, fmaxf(fmaxf(v.x, v.y), fmaxf(v.z, v.w)));
            }
        }
        for (int off = 32; off > 0; off >>= 1) {
            vmin = fminf(vmin, __shfl_down(vmin, off));
            vmax = fmaxf(vmax, __shfl_down(vmax, off));
        }
        if ((tid & 63) == 0) { smin[tid >> 6] = vmin; smax[tid >> 6] = vmax; }
        __syncthreads();
        if (tid == 0) {
            part[(ch * NSLOT + 32) * 2]     = fminf(fminf(smin[0], smin[1]), fminf(smin[2], smin[3]));
            part[(ch * NSLOT + 32) * 2 + 1] = fmaxf(fmaxf(smax[0], smax[1]), fmaxf(smax[2], smax[3]));
        }
    }
}

// ============ L2: gray (both x_pairs channels) + combine + argmin ============
__global__ __launch_bounds__(256) void k_gray2(const float* __restrict__ x,
                                               const float* __restrict__ part,
                                               const int* __restrict__ dates,
                                               float* __restrict__ xp) {
    int bid = blockIdx.x;
    int nt  = bid >> 6;
    int g   = (bid & 63) * 256 + threadIdx.x;
    int n   = nt / TT;

    int bestv = 0x7FFFFFFF, best = 0;
    for (int t = 0; t < TT; ++t) {
        int d = 182 - dates[n * TT + t];
        d = d < 0 ? -d : d;
        if (d < bestv) { bestv = d; best = t; }
    }
    int nt2 = n * TT + best;

    float sA[3], sB[3], biasA = 0.f, biasB = 0.f;
    const float w[3] = {0.299f, 0.587f, 0.114f};
    #pragma unroll
    for (int c = 0; c < 3; ++c) {
        int chA = nt * 3 + c, chB = nt2 * 3 + c;
        float mnA = 1e30f, mxA = -1e30f, mnB = 1e30f, mxB = -1e30f;
        #pragma unroll
        for (int s = 0; s < NSLOT; ++s) {
            mnA = fminf(mnA, part[(chA * NSLOT + s) * 2]);
            mxA = fmaxf(mxA, part[(chA * NSLOT + s) * 2 + 1]);
            mnB = fminf(mnB, part[(chB * NSLOT + s) * 2]);
            mxB = fmaxf(mxB, part[(chB * NSLOT + s) * 2 + 1]);
        }
        sA[c] = w[c] / (mxA - mnA + 1e-8f);  biasA -= mnA * sA[c];
        sB[c] = w[c] / (mxB - mnB + 1e-8f);  biasB -= mnB * sB[c];
    }

    const float4* pA0 = (const float4*)(x + ((size_t)nt  * CC + 0) * HWP);
    const float4* pA1 = (const float4*)(x + ((size_t)nt  * CC + 1) * HWP);
    const float4* pA2 = (const float4*)(x + ((size_t)nt  * CC + 2) * HWP);
    const float4* pB0 = (const float4*)(x + ((size_t)nt2 * CC + 0) * HWP);
    const float4* pB1 = (const float4*)(x + ((size_t)nt2 * CC + 1) * HWP);
    const float4* pB2 = (const float4*)(x + ((size_t)nt2 * CC + 2) * HWP);

    float4 v0 = pA0[g], v1 = pA1[g], v2 = pA2[g];
    float4 rA;
    rA.x = v0.x * sA[0] + v1.x * sA[1] + v2.x * sA[2] + biasA;
    rA.y = v0.y * sA[0] + v1.y * sA[1] + v2.y * sA[2] + biasA;
    rA.z = v0.z * sA[0] + v1.z * sA[1] + v2.z * sA[2] + biasA;
    rA.w = v0.w * sA[0] + v1.w * sA[1] + v2.w * sA[2] + biasA;
    ((float4*)(xp + ((size_t)nt * 2) * HWP))[g] = rA;

    float4 u0 = pB0[g], u1 = pB1[g], u2 = pB2[g];   // ~3 MB unique per n -> L2/L3 hot
    float4 rB;
    rB.x = u0.x * sB[0] + u1.x * sB[1] + u2.x * sB[2] + biasB;
    rB.y = u0.y * sB[0] + u1.y * sB[1] + u2.y * sB[2] + biasB;
    rB.z = u0.z * sB[0] + u1.z * sB[1] + u2.z * sB[2] + biasB;
    rB.w = u0.w * sB[0] + u1.w * sB[1] + u2.w * sB[2] + biasB;
    ((float4*)(xp + ((size_t)nt * 2 + 1) * HWP))[g] = rB;
}

extern "C" void kernel_launch(void* const* d_in, const int* in_sizes, int n_in,
                              void* d_out, int out_size, void* d_ws, size_t ws_size,
                              hipStream_t stream) {
    const float* x      = (const float*)d_in[0];
    const int*   dates  = (const int*)d_in[1];
    const float* thetas = (const float*)d_in[2];
    float* out1 = (float*)d_out;                      // (n,t,c,h,w) shifted output
    float* out2 = out1 + (size_t)NT * CC * HWP;       // x_pairs (n,t,2,h,w)
    float* part = (float*)d_ws;                       // [288][33][2] floats

    k_shift_mm<<<6432, 256, 0, stream>>>(x, thetas, out1, part);
    k_gray2   <<<6144, 256, 0, stream>>>(x, part, dates, out2);
}